// Round 4
// baseline (155.482 us; speedup 1.0000x reference)
//
#include <hip/hip_runtime.h>
#include <hip/hip_fp16.h>
#include <cmath>

#define NLOD 10

// ---------------------------------------------------------------------------
// LDS layout (SoA, all compile-time):
//   f01 array (half2 per entry, 4 B):  bytes      0 .. 39020
//   f2  array (half  per entry, 2 B):  bytes  39020 .. 58530
// Entry order within each array:
//   [hashed levels 4..9]  4825 entries
//   [dense grids 0..3]    4930 vertices   (levels 0..3 de-hashed at staging)
// 58532 B/block -> two 1024-thread blocks/CU (117 KB of 160 KB), full
// 2048-thread occupancy.
//
// Why SoA instead of 8 B AoS entries: every gather was a ds_read_b64 --
// 512 B/wave over 32x4B banks, >=2 lanes/bank even conflict-free, and a
// heavy conflict tail on random addresses (1.6e7 conflict cycles measured,
// ~45% of runtime).  ds_read_b32 + ds_read_u16 average 2 lanes/bank, which
// is conflict-free on CDNA4, and move 25% fewer bytes (no pad).
// ---------------------------------------------------------------------------
static constexpr int HSIZES[6] = {324, 529, 900, 1024, 1024, 1024}; // levels 4..9
static constexpr int HENT[6]   = {0, 324, 853, 1753, 2777, 3801};   // entry offsets
static constexpr int TOTAL_ENTRIES = 9755;                           // 4825 + 4930
static constexpr int F2OFS = TOTAL_ENTRIES * 4;                      // 39020
// dense grids: res 7,8,11,14 -> cubes 343,512,1331,2744; entry offsets:
//   4825, 5168, 5680, 7011

struct ResArr { int r[NLOD]; };

// Three v_fma_mix_f32 consume the f16 halves in place via op_sel
// (numerically identical to fpext+fma, both exact/fused).
// r01 = {f0,f1} packed;  r2 = zero-extended u16 holding f2 in its low half.
__device__ __forceinline__ void fmix_accum(unsigned r01, unsigned r2, float wt,
                                           float& a0, float& a1, float& a2)
{
    asm("v_fma_mix_f32 %0, %1, %2, %0 op_sel_hi:[1,0,0]"
        : "+v"(a0) : "v"(r01), "v"(wt));
    asm("v_fma_mix_f32 %0, %1, %2, %0 op_sel:[1,0,0] op_sel_hi:[1,0,0]"
        : "+v"(a1) : "v"(r01), "v"(wt));
    asm("v_fma_mix_f32 %0, %1, %2, %0 op_sel_hi:[1,0,0]"
        : "+v"(a2) : "v"(r2), "v"(wt));
}

// ---------------------------------------------------------------------------
// Dense (de-hashed) levels 0..3.  ENT = entry offset of this level's grid.
// base4 = linear*4 computed exactly in float (2 fma + cvt, all terms < 2^24);
// base2 = base4>>1.  Corner deltas are compile-time immediates on both reads.
// ---------------------------------------------------------------------------
template <int RES, int ENT>
__device__ __forceinline__ void dense_accum(const char* lds,
                                            float px, float py, float pz,
                                            float& a0, float& a1, float& a2)
{
    constexpr float S = (float)(RES - 1);
    float fx = px * S, fy = py * S, fz = pz * S;

    // clip(floor(x),0,res-2) == floor(x) here, exactly (px in [0,1),
    // res-1 in [6,64]; the product never rounds up to res-1).
    float gx = floorf(fx), gy = floorf(fy), gz = floorf(fz);
    float wx = fx - gx, wy = fy - gy, wz = fz - gz;

    float lin = fmaf(gx, (float)(RES * RES * 4),
                 fmaf(gy, (float)(RES * 4), gz * 4.0f));
    unsigned base4 = (unsigned)lin;   // exact: lin is a non-negative integer
    unsigned base2 = base4 >> 1;

    float wx0 = 1.0f - wx, wy0 = 1.0f - wy, wz0 = 1.0f - wz;
    float w00 = wx0 * wy0, w01 = wx0 * wy, w10 = wx * wy0, w11 = wx * wy;

#define DCORNER(I, J, K, WT)                                                     \
    {                                                                            \
        constexpr int D = (I) * RES * RES + (J) * RES + (K);                     \
        unsigned r01 = *reinterpret_cast<const unsigned*>(                       \
                           lds + base4 + ((ENT + D) * 4));                       \
        unsigned r2  = *reinterpret_cast<const unsigned short*>(                 \
                           lds + base2 + (F2OFS + (ENT + D) * 2));               \
        fmix_accum(r01, r2, (WT), a0, a1, a2);                                   \
    }

    // reference OFFSETS order: (i,j,k) for i in(0,1) j in(0,1) k in(0,1)
    DCORNER(0, 0, 0, w00 * wz0)
    DCORNER(0, 0, 1, w00 * wz)
    DCORNER(0, 1, 0, w01 * wz0)
    DCORNER(0, 1, 1, w01 * wz)
    DCORNER(1, 0, 0, w10 * wz0)
    DCORNER(1, 0, 1, w10 * wz)
    DCORNER(1, 1, 0, w11 * wz0)
    DCORNER(1, 1, 1, w11 * wz)
#undef DCORNER
}

// ---------------------------------------------------------------------------
// Hashed levels 4..9.  ENT = entry offset of this level's table.
// Pow2 folds the *4 byte-scale into the hash components
// ((h<<2) & ((SIZE-1)*4) == 4*(h & (SIZE-1)) since shift distributes over
// xor); non-pow2 uses the constexpr-divisor magic-mod.  o2 = o4>>1.
// ---------------------------------------------------------------------------
template <int SIZE, int ENT>
__device__ __forceinline__ void level_accum(const char* lds, int res,
                                            float px, float py, float pz,
                                            float& a0, float& a1, float& a2)
{
    constexpr bool POW2 = (SIZE & (SIZE - 1)) == 0;
    constexpr unsigned P1 = 2654435761u, P2 = 805459861u;

    const float s = (float)(res - 1);
    float fx = px * s, fy = py * s, fz = pz * s;

    float gx = floorf(fx), gy = floorf(fy), gz = floorf(fz);
    float wx = fx - gx, wy = fy - gy, wz = fz - gz;

    unsigned ux = (unsigned)(int)gx;
    unsigned uy = (unsigned)(int)gy;
    unsigned uz = (unsigned)(int)gz;

    unsigned hx0, hx1, hy0, hy1, hz0, hz1;
    if constexpr (POW2) {
        hx0 = ux << 2;        hx1 = hx0 + 4u;
        hy0 = uy * (P1 * 4u); hy1 = hy0 + (P1 * 4u);
        hz0 = uz * (P2 * 4u); hz1 = hz0 + (P2 * 4u);
    } else {
        hx0 = ux;       hx1 = ux + 1u;
        hy0 = uy * P1;  hy1 = hy0 + P1;
        hz0 = uz * P2;  hz1 = hz0 + P2;
    }
    unsigned h00 = hx0 ^ hy0, h01 = hx0 ^ hy1;
    unsigned h10 = hx1 ^ hy0, h11 = hx1 ^ hy1;

    float wx0 = 1.0f - wx, wy0 = 1.0f - wy, wz0 = 1.0f - wz;
    float w00 = wx0 * wy0, w01 = wx0 * wy, w10 = wx * wy0, w11 = wx * wy;

    auto corner = [&](unsigned h, float wt) {
        unsigned o4;
        if constexpr (POW2) o4 = h & (unsigned)((SIZE - 1) * 4);
        else                o4 = (h % (unsigned)SIZE) * 4u;  // magic mul
        unsigned o2 = o4 >> 1;
        unsigned r01 = *reinterpret_cast<const unsigned*>(
                           lds + o4 + (ENT * 4));
        unsigned r2  = *reinterpret_cast<const unsigned short*>(
                           lds + o2 + (F2OFS + ENT * 2));
        fmix_accum(r01, r2, wt, a0, a1, a2);
    };

    corner(h00 ^ hz0, w00 * wz0);
    corner(h00 ^ hz1, w00 * wz);
    corner(h01 ^ hz0, w01 * wz0);
    corner(h01 ^ hz1, w01 * wz);
    corner(h10 ^ hz0, w10 * wz0);
    corner(h10 ^ hz1, w10 * wz);
    corner(h11 ^ hz0, w11 * wz0);
    corner(h11 ^ hz1, w11 * wz);
}

// Write one staged entry into the SoA arrays.
__device__ __forceinline__ void stage_entry(char* lds, int entry,
                                            float s0, float s1, float s2)
{
    *reinterpret_cast<__half2*>(lds + entry * 4) = __floats2half2_rn(s0, s1);
    *reinterpret_cast<__half*>(lds + F2OFS + entry * 2) = __float2half_rn(s2);
}

// Stage one dense de-hashed grid: per vertex (x,y,z), compute the Instant-NGP
// hash once, gather the codebook entry, compress to f16, store at the linear
// vertex index.  ~5 vertices/thread for 1024-thread blocks.
template <int RES, int SIZE, int ENT>
__device__ __forceinline__ void stage_dense(const float* __restrict__ src,
                                            char* lds)
{
    constexpr unsigned P1 = 2654435761u, P2 = 805459861u;
    for (int v = threadIdx.x; v < RES * RES * RES; v += 1024) {
        int z = v % RES;
        int t = v / RES;
        int y = t % RES;
        int x = t / RES;
        unsigned h = (unsigned)x ^ ((unsigned)y * P1) ^ ((unsigned)z * P2);
        unsigned idx = h % (unsigned)SIZE;        // constexpr divisor
        const float* s = src + idx * 3;
        stage_entry(lds, ENT + v, s[0], s[1], s[2]);
    }
}

__global__ __launch_bounds__(1024, 8)
void hashgrid_kernel(const float* __restrict__ pts,
                     const float* __restrict__ c0, const float* __restrict__ c1,
                     const float* __restrict__ c2, const float* __restrict__ c3,
                     const float* __restrict__ c4, const float* __restrict__ c5,
                     const float* __restrict__ c6, const float* __restrict__ c7,
                     const float* __restrict__ c8, const float* __restrict__ c9,
                     float* __restrict__ out, int npts, ResArr res)
{
    __shared__ unsigned ldsbuf[(TOTAL_ENTRIES * 6 + 3) / 4 + 1];  // 58532 B
    char* lds = reinterpret_cast<char*>(ldsbuf);

    // ---- stage hashed levels 4..9 (copy + compress) ----
    {
        const float* hs[6] = {c4, c5, c6, c7, c8, c9};
#pragma unroll
        for (int L = 0; L < 6; ++L) {
            for (int e = threadIdx.x; e < HSIZES[L]; e += 1024) {
                const float* s = hs[L] + e * 3;
                stage_entry(lds, HENT[L] + e, s[0], s[1], s[2]);
            }
        }
    }
    // ---- stage dense de-hashed grids, levels 0..3 ----
    stage_dense< 7,  49, 4825>(c0, lds);
    stage_dense< 8,  64, 5168>(c1, lds);
    stage_dense<11, 121, 5680>(c2, lds);
    stage_dense<14, 196, 7011>(c3, lds);
    __syncthreads();

    // 512 blocks x 1024 thr (exactly 2 blocks/CU), 2 points/thread/iter,
    // 2 iterations for npts = 2M.  Immediate-consume corner structure:
    // at 64-VGPR budget the compiler's own schedule beats any source-level
    // phasing (rounds 2/3 evidence: arrays spill to scratch).
    const int S = gridDim.x * blockDim.x;
    for (int n = blockIdx.x * blockDim.x + threadIdx.x; n < npts; n += 2 * S) {
        const int m = n + S;
        const bool hasB = (m < npts);
        const int mc = hasB ? m : n;      // clamp: B duplicates A, store suppressed

        float ax = pts[n * 3 + 0], ay = pts[n * 3 + 1], az = pts[n * 3 + 2];
        float bx = pts[mc * 3 + 0], by = pts[mc * 3 + 1], bz = pts[mc * 3 + 2];

        float A0 = 0.0f, A1 = 0.0f, A2 = 0.0f;
        float B0 = 0.0f, B1 = 0.0f, B2 = 0.0f;

        // levels 0..3: dense de-hashed grids (no hash, no modulo; corner
        // deltas are offset immediates on both SoA reads)
#define DLEVEL2(RES, ENT)                                        \
        dense_accum<RES, ENT>(lds, ax, ay, az, A0, A1, A2);      \
        dense_accum<RES, ENT>(lds, bx, by, bz, B0, B1, B2);

        DLEVEL2( 7, 4825)
        DLEVEL2( 8, 5168)
        DLEVEL2(11, 5680)
        DLEVEL2(14, 7011)
#undef DLEVEL2

        // levels 4..9: hashed lookups (magic-mod for 324/529/900, masked
        // pow2 for the 1024s)
#define HLEVEL2(SZ, HL)                                                         \
        level_accum<SZ, HENT[HL]>(lds, res.r[(HL) + 4], ax, ay, az, A0, A1, A2);\
        level_accum<SZ, HENT[HL]>(lds, res.r[(HL) + 4], bx, by, bz, B0, B1, B2);

        HLEVEL2( 324, 0)
        HLEVEL2( 529, 1)
        HLEVEL2( 900, 2)
        HLEVEL2(1024, 3)
        HLEVEL2(1024, 4)
        HLEVEL2(1024, 5)
#undef HLEVEL2

        out[n * 3 + 0] = A0;
        out[n * 3 + 1] = A1;
        out[n * 3 + 2] = A2;
        if (hasB) {
            out[m * 3 + 0] = B0;
            out[m * 3 + 1] = B1;
            out[m * 3 + 2] = B2;
        }
    }
}

extern "C" void kernel_launch(void* const* d_in, const int* in_sizes, int n_in,
                              void* d_out, int out_size, void* d_ws, size_t ws_size,
                              hipStream_t stream)
{
    const float* pts = (const float*)d_in[0];
    const int npts = in_sizes[0] / 3;

    // Replicate numpy's exact double-precision LOD computation (glibc libm):
    // LOD 9 sits at 6*b^9 == 64.0 +/- ~1e-14, floor() is boundary-sensitive.
    // (Only levels 4..9 are consumed at runtime; 0..3 are compile-time dense.)
    ResArr ra;
    const double b = exp((log(64.0) - log(6.0)) / 9.0);
    for (int l = 0; l < NLOD; ++l)
        ra.r[l] = (int)(1.0 + floor(6.0 * pow(b, (double)l)));

    // 512 blocks x 1024 thr: 2 blocks/CU (117 KB LDS), 32 waves/CU.
    hashgrid_kernel<<<dim3(512), dim3(1024), 0, stream>>>(
        pts,
        (const float*)d_in[1], (const float*)d_in[2], (const float*)d_in[3],
        (const float*)d_in[4], (const float*)d_in[5], (const float*)d_in[6],
        (const float*)d_in[7], (const float*)d_in[8], (const float*)d_in[9],
        (const float*)d_in[10],
        (float*)d_out, npts, ra);
}

// Round 6
// 140.029 us; speedup vs baseline: 1.1104x; 1.1104x over previous
//
#include <hip/hip_runtime.h>
#include <hip/hip_fp16.h>
#include <cmath>

#define NLOD 10

// ---------------------------------------------------------------------------
// LDS layout (AoS 8 B entries -- R4 proved sub-dword SoA gathers serialize in
// the banks; ds_read_b64 is the right shape):
//   [hashed levels 4..9]  4825 entries   bytes      0 .. 38600
//   [dense grids 0..3]    4930 vertices  bytes  38600 .. 78040
// Hashed levels come FIRST so every ds_read offset immediate stays < 65536.
//
// Levels 0..3 are staged DE-HASHED (hash+mod once per vertex per block at
// staging; hot loop addresses by linear vertex coordinate).
//
// Occupancy/ILP tradeoff (round-4 decision): __launch_bounds__(1024, 4)
// lifts the VGPR cap to 128 so the phased structure below
//   [addr+weights A,B] -> [16 ds_read_b64 in flight] -> [48 v_fma_mix]
// lives entirely in registers (~94 live; at the old 64-cap it spilled to
// scratch: +7.6 MB FETCH / +19.8 MB WRITE measured in round 3).
// 16 waves/CU remain; each wave carries a full level of gathers in flight,
// so ILP replaces the lost TLP while the LDS pipe stays saturated.
// 512 blocks = exactly 2 sequential 1-block-per-CU rounds (staging runs
// twice; ~9.7K entries/block is ~2 us, negligible).
// ---------------------------------------------------------------------------
static constexpr int HSIZES[6] = {324, 529, 900, 1024, 1024, 1024}; // levels 4..9
static constexpr int HENT[6]   = {0, 324, 853, 1753, 2777, 3801};   // entry offsets
static constexpr int TOTAL_ENTRIES = 9755;                           // 4825 + 4930
// LDS bytes = 9755 * 8 = 78040

struct ResArr { int r[NLOD]; };

// Three v_fma_mix_f32 consume the f16 halves in place via op_sel
// (numerically identical to fpext+fma, both exact/fused).
__device__ __forceinline__ void fmix_accum(uint2 raw, float wt,
                                           float& a0, float& a1, float& a2)
{
    asm("v_fma_mix_f32 %0, %1, %2, %0 op_sel_hi:[1,0,0]"
        : "+v"(a0) : "v"(raw.x), "v"(wt));
    asm("v_fma_mix_f32 %0, %1, %2, %0 op_sel:[1,0,0] op_sel_hi:[1,0,0]"
        : "+v"(a1) : "v"(raw.x), "v"(wt));
    asm("v_fma_mix_f32 %0, %1, %2, %0 op_sel_hi:[1,0,0]"
        : "+v"(a2) : "v"(raw.y), "v"(wt));
}

// Shared weight computation.  Corner order matches reference OFFSETS:
// c = 4i+2j+k, (i,j,k) lexicographic.
__device__ __forceinline__ void make_weights(float wx, float wy, float wz,
                                             float (&wt)[8])
{
    float wx0 = 1.0f - wx, wy0 = 1.0f - wy, wz0 = 1.0f - wz;
    float w00 = wx0 * wy0, w01 = wx0 * wy, w10 = wx * wy0, w11 = wx * wy;
    wt[0] = w00 * wz0; wt[1] = w00 * wz;
    wt[2] = w01 * wz0; wt[3] = w01 * wz;
    wt[4] = w10 * wz0; wt[5] = w10 * wz;
    wt[6] = w11 * wz0; wt[7] = w11 * wz;
}

// ---------------------------------------------------------------------------
// Hashed levels 4..9: address phase.  ofs[c] = byte offset into this level's
// table.  Pow2 folds the *8 byte scale into the hash components
// ((h<<3) mod (8*SIZE) == 8*(h mod SIZE) iff SIZE pow2); non-pow2 uses the
// constexpr-divisor magic-mod.
// ---------------------------------------------------------------------------
template <int SIZE>
__device__ __forceinline__ void hash_setup(int res, float px, float py, float pz,
                                           unsigned (&ofs)[8], float (&wt)[8])
{
    constexpr bool POW2 = (SIZE & (SIZE - 1)) == 0;
    constexpr unsigned P1 = 2654435761u, P2 = 805459861u;

    const float s = (float)(res - 1);
    float fx = px * s, fy = py * s, fz = pz * s;

    // clip(floor(x),0,res-2) == floor(x) here, exactly (px in [0,1),
    // res-1 in [6,64]; the product never rounds up to res-1).
    float gx = floorf(fx), gy = floorf(fy), gz = floorf(fz);
    float wx = fx - gx, wy = fy - gy, wz = fz - gz;

    unsigned ux = (unsigned)(int)gx;
    unsigned uy = (unsigned)(int)gy;
    unsigned uz = (unsigned)(int)gz;

    unsigned hx0, hx1, hy0, hy1, hz0, hz1;
    if constexpr (POW2) {
        hx0 = ux << 3;        hx1 = hx0 + 8u;
        hy0 = uy * (P1 * 8u); hy1 = hy0 + (P1 * 8u);
        hz0 = uz * (P2 * 8u); hz1 = hz0 + (P2 * 8u);
    } else {
        hx0 = ux;       hx1 = ux + 1u;
        hy0 = uy * P1;  hy1 = hy0 + P1;
        hz0 = uz * P2;  hz1 = hz0 + P2;
    }
    unsigned h00 = hx0 ^ hy0, h01 = hx0 ^ hy1;
    unsigned h10 = hx1 ^ hy0, h11 = hx1 ^ hy1;

    unsigned h[8] = { h00 ^ hz0, h00 ^ hz1, h01 ^ hz0, h01 ^ hz1,
                      h10 ^ hz0, h10 ^ hz1, h11 ^ hz0, h11 ^ hz1 };
#pragma unroll
    for (int c = 0; c < 8; ++c) {
        if constexpr (POW2) ofs[c] = h[c] & (unsigned)((SIZE - 1) * 8);
        else                ofs[c] = (h[c] % (unsigned)SIZE) * 8u;
    }
    make_weights(wx, wy, wz, wt);
}

// Hashed level, two points: addr A, addr B, 16 loads in flight, 48 fma.
template <int SIZE>
__device__ __forceinline__ void hash2(const char* __restrict__ cb, int res,
    float ax, float ay, float az, float& A0, float& A1, float& A2,
    float bx, float by, float bz, float& B0, float& B1, float& B2)
{
    unsigned oa[8], ob[8];
    float    wa[8], wb[8];
    hash_setup<SIZE>(res, ax, ay, az, oa, wa);
    hash_setup<SIZE>(res, bx, by, bz, ob, wb);

    uint2 ra[8], rb[8];
#pragma unroll
    for (int c = 0; c < 8; ++c)
        ra[c] = *reinterpret_cast<const uint2*>(cb + oa[c]);
#pragma unroll
    for (int c = 0; c < 8; ++c)
        rb[c] = *reinterpret_cast<const uint2*>(cb + ob[c]);

#pragma unroll
    for (int c = 0; c < 8; ++c) fmix_accum(ra[c], wa[c], A0, A1, A2);
#pragma unroll
    for (int c = 0; c < 8; ++c) fmix_accum(rb[c], wb[c], B0, B1, B2);
}

// ---------------------------------------------------------------------------
// Dense (de-hashed) levels 0..3.  base = ((gx*RES+gy)*RES+gz)*8 computed
// exactly in float (2 fma + cvt; all terms < 2^24); corner deltas are
// compile-time constants folded into the ds_read offset immediates.
// ---------------------------------------------------------------------------
template <int RES>
__device__ __forceinline__ void dense_setup(float px, float py, float pz,
                                            unsigned& base, float (&wt)[8])
{
    constexpr float S = (float)(RES - 1);
    float fx = px * S, fy = py * S, fz = pz * S;
    float gx = floorf(fx), gy = floorf(fy), gz = floorf(fz);
    float wx = fx - gx, wy = fy - gy, wz = fz - gz;

    float lin = fmaf(gx, (float)(RES * RES * 8),
                 fmaf(gy, (float)(RES * 8), gz * 8.0f));
    base = (unsigned)lin;   // exact: lin is a non-negative integer < 2^24
    make_weights(wx, wy, wz, wt);
}

template <int RES, int LBASE>
__device__ __forceinline__ void dense2(const char* __restrict__ lds,
    float ax, float ay, float az, float& A0, float& A1, float& A2,
    float bx, float by, float bz, float& B0, float& B1, float& B2)
{
    unsigned baA, baB;
    float wa[8], wb[8];
    dense_setup<RES>(ax, ay, az, baA, wa);
    dense_setup<RES>(bx, by, bz, baB, wb);

    uint2 ra[8], rb[8];
#pragma unroll
    for (int c = 0; c < 8; ++c) {
        const int d = LBASE + (((c >> 2) * RES * RES + ((c >> 1) & 1) * RES + (c & 1)) * 8);
        ra[c] = *reinterpret_cast<const uint2*>(lds + baA + d);
    }
#pragma unroll
    for (int c = 0; c < 8; ++c) {
        const int d = LBASE + (((c >> 2) * RES * RES + ((c >> 1) & 1) * RES + (c & 1)) * 8);
        rb[c] = *reinterpret_cast<const uint2*>(lds + baB + d);
    }

#pragma unroll
    for (int c = 0; c < 8; ++c) fmix_accum(ra[c], wa[c], A0, A1, A2);
#pragma unroll
    for (int c = 0; c < 8; ++c) fmix_accum(rb[c], wb[c], B0, B1, B2);
}

// Stage one dense de-hashed grid: per vertex (x,y,z), compute the Instant-NGP
// hash once, gather the codebook entry, compress to f16, store at the linear
// vertex index.  ~5 vertices/thread for 1024-thread blocks.
template <int RES, int SIZE, int ENT>
__device__ __forceinline__ void stage_dense(const float* __restrict__ src,
                                            __half* cbh)
{
    constexpr unsigned P1 = 2654435761u, P2 = 805459861u;
    for (int v = threadIdx.x; v < RES * RES * RES; v += 1024) {
        int z = v % RES;
        int t = v / RES;
        int y = t % RES;
        int x = t / RES;
        unsigned h = (unsigned)x ^ ((unsigned)y * P1) ^ ((unsigned)z * P2);
        unsigned idx = h % (unsigned)SIZE;        // constexpr divisor
        const float* s = src + idx * 3;
        __half2* d = reinterpret_cast<__half2*>(cbh + (ENT + v) * 4);
        d[0] = __floats2half2_rn(s[0], s[1]);
        d[1] = __floats2half2_rn(s[2], 0.0f);
    }
}

__global__ __launch_bounds__(1024, 4)
void hashgrid_kernel(const float* __restrict__ pts,
                     const float* __restrict__ c0, const float* __restrict__ c1,
                     const float* __restrict__ c2, const float* __restrict__ c3,
                     const float* __restrict__ c4, const float* __restrict__ c5,
                     const float* __restrict__ c6, const float* __restrict__ c7,
                     const float* __restrict__ c8, const float* __restrict__ c9,
                     float* __restrict__ out, int npts, ResArr res)
{
    __shared__ __half cbh[TOTAL_ENTRIES * 4];   // 78040 B
    const char* lds = reinterpret_cast<const char*>(cbh);

    // ---- stage hashed levels 4..9 (copy + compress) ----
    {
        const float* hs[6] = {c4, c5, c6, c7, c8, c9};
#pragma unroll
        for (int L = 0; L < 6; ++L) {
            for (int e = threadIdx.x; e < HSIZES[L]; e += 1024) {
                const float* s = hs[L] + e * 3;
                __half2* d = reinterpret_cast<__half2*>(cbh + (HENT[L] + e) * 4);
                d[0] = __floats2half2_rn(s[0], s[1]);
                d[1] = __floats2half2_rn(s[2], 0.0f);
            }
        }
    }
    // ---- stage dense de-hashed grids, levels 0..3 ----
    stage_dense< 7,  49, 4825>(c0, cbh);
    stage_dense< 8,  64, 5168>(c1, cbh);
    stage_dense<11, 121, 5680>(c2, cbh);
    stage_dense<14, 196, 7011>(c3, cbh);
    __syncthreads();

    // 512 blocks x 1024 thr, 2 points/thread/iter, 2 iterations for 2M pts.
    // At 128-VGPR cap only one block is resident per CU at a time; the grid
    // drains in exactly 2 uniform rounds.
    const int S = gridDim.x * blockDim.x;
    for (int n = blockIdx.x * blockDim.x + threadIdx.x; n < npts; n += 2 * S) {
        const int m = n + S;
        const bool hasB = (m < npts);
        const int mc = hasB ? m : n;      // clamp: B duplicates A, store suppressed

        float ax = pts[n * 3 + 0], ay = pts[n * 3 + 1], az = pts[n * 3 + 2];
        float bx = pts[mc * 3 + 0], by = pts[mc * 3 + 1], bz = pts[mc * 3 + 2];

        float A0 = 0.0f, A1 = 0.0f, A2 = 0.0f;
        float B0 = 0.0f, B1 = 0.0f, B2 = 0.0f;

        // levels 0..3: dense de-hashed grids
#define DLEVEL(RES, ENT)                                    \
        dense2<RES, (ENT) * 8>(lds, ax, ay, az, A0, A1, A2, \
                                    bx, by, bz, B0, B1, B2);
        DLEVEL( 7, 4825)
        DLEVEL( 8, 5168)
        DLEVEL(11, 5680)
        DLEVEL(14, 7011)
#undef DLEVEL

        // levels 4..9: hashed lookups (magic-mod for 324/529/900, masked
        // pow2 for the 1024s)
#define HLEVEL(SZ, HL)                                                 \
        hash2<SZ>(lds + HENT[HL] * 8, res.r[(HL) + 4],                 \
                  ax, ay, az, A0, A1, A2, bx, by, bz, B0, B1, B2);
        HLEVEL( 324, 0)
        HLEVEL( 529, 1)
        HLEVEL( 900, 2)
        HLEVEL(1024, 3)
        HLEVEL(1024, 4)
        HLEVEL(1024, 5)
#undef HLEVEL

        out[n * 3 + 0] = A0;
        out[n * 3 + 1] = A1;
        out[n * 3 + 2] = A2;
        if (hasB) {
            out[m * 3 + 0] = B0;
            out[m * 3 + 1] = B1;
            out[m * 3 + 2] = B2;
        }
    }
}

extern "C" void kernel_launch(void* const* d_in, const int* in_sizes, int n_in,
                              void* d_out, int out_size, void* d_ws, size_t ws_size,
                              hipStream_t stream)
{
    const float* pts = (const float*)d_in[0];
    const int npts = in_sizes[0] / 3;

    // Replicate numpy's exact double-precision LOD computation (glibc libm):
    // LOD 9 sits at 6*b^9 == 64.0 +/- ~1e-14, floor() is boundary-sensitive.
    // (Only levels 4..9 are consumed at runtime; 0..3 are compile-time dense.)
    ResArr ra;
    const double b = exp((log(64.0) - log(6.0)) / 9.0);
    for (int l = 0; l < NLOD; ++l)
        ra.r[l] = (int)(1.0 + floor(6.0 * pow(b, (double)l)));

    hashgrid_kernel<<<dim3(512), dim3(1024), 0, stream>>>(
        pts,
        (const float*)d_in[1], (const float*)d_in[2], (const float*)d_in[3],
        (const float*)d_in[4], (const float*)d_in[5], (const float*)d_in[6],
        (const float*)d_in[7], (const float*)d_in[8], (const float*)d_in[9],
        (const float*)d_in[10],
        (float*)d_out, npts, ra);
}